// Round 20
// baseline (595.628 us; speedup 1.0000x reference)
//
#include <hip/hip_runtime.h>
#include <hip/hip_bf16.h>
#include <stdint.h>

#define M_TOTAL 16384
#define N_TOTAL 4096
#define K_TOTAL 4096
#define NSTEP (K_TOTAL / 64)   // 64 K-steps of 64
#define NT32 (K_TOTAL / 32)

typedef __attribute__((ext_vector_type(8))) short bf16x8;
typedef __attribute__((ext_vector_type(4))) float f32x4;
typedef __attribute__((ext_vector_type(16))) float f32x16;

__device__ __forceinline__ void gload_lds16(const void* g, void* l) {
    __builtin_amdgcn_global_load_lds(
        (const __attribute__((address_space(1))) uint32_t*)g,
        (__attribute__((address_space(3))) uint32_t*)l, 16, 0, 0);
}

// ---------------------------------------------------------------------------
// Kernel 0: X f32 -> bf16.
// ---------------------------------------------------------------------------
__global__ __launch_bounds__(256) void k_convX(const float* __restrict__ X,
                                               __hip_bfloat16* __restrict__ Xb) {
    size_t t = (size_t)blockIdx.x * 256 + threadIdx.x;
    const float* p = X + t * 8;
    float4 a = *(const float4*)p;
    float4 b = *(const float4*)(p + 4);
    __hip_bfloat162 o[4] = {
        __float22bfloat162_rn(make_float2(a.x, a.y)),
        __float22bfloat162_rn(make_float2(a.z, a.w)),
        __float22bfloat162_rn(make_float2(b.x, b.y)),
        __float22bfloat162_rn(make_float2(b.z, b.w))};
    *(int4*)(Xb + t * 8) = *(int4*)&o[0];
}

// ---------------------------------------------------------------------------
// Kernel 1: packed int4 -> bf16 W[N][K].
// ---------------------------------------------------------------------------
__global__ __launch_bounds__(256) void k_dequant(const int* __restrict__ pw,
                                                 const float* __restrict__ sc,
                                                 __hip_bfloat16* __restrict__ W) {
    int t = blockIdx.x * 256 + threadIdx.x;
    int row = t >> 8;
    int w0 = (t & 255) << 3;
    const int* p = pw + (size_t)row * 2048 + w0;
    int4 q0 = *(const int4*)p;
    int4 q1 = *(const int4*)(p + 4);
    float s = sc[row * 128 + (w0 >> 4)];
    float ns8 = -8.0f * s;
    int w[8] = {q0.x, q0.y, q0.z, q0.w, q1.x, q1.y, q1.z, q1.w};
    __hip_bfloat162 o[8];
#pragma unroll
    for (int i = 0; i < 8; ++i) {
        float lo = fmaf((float)(w[i] & 15), s, ns8);
        float hi = fmaf((float)(w[i] >> 4), s, ns8);
        o[i] = __float22bfloat162_rn(make_float2(lo, hi));
    }
    __hip_bfloat16* dst = W + (size_t)row * 4096 + w0 * 2;
    *(int4*)dst = *(int4*)&o[0];
    *(int4*)(dst + 8) = *(int4*)&o[4];
}

// ---------------------------------------------------------------------------
// Kernel 2 (tier A): r18's exact schedule (single-barrier 8-phase, stage
// rotation, VMW(2) ledger, row-major + 3-bit-XOR layout — all verified)
// with 32x32x16 MFMA (2.46e-4 vs 2.96e-4 cyc/FLOP; r13's null was
// layout-confounded: 5.03e7 conflicts = ~768 cyc/step ate the pipe gain).
//
// Per-wave 128x64 = 4ar x 2bc grid of 32x32 tiles; acc = f32x16[4][2].
// Reads per K64-step: A 4ar x 4kc = 16 b128, B 2bc x 4kc = 8 (same 24 as
// r18, same per-phase counts 12/4/8/0). MFMA: 8 per phase (32/step).
// Frag layout: A/B row=lane&31, k=(lane>>5)*8+e; C/D col=lane&31,
// row=(reg&3)+8*(reg>>2)+4*(lane>>5)  [m74/m101; r13 refcheck-passed].
//
// Bank check (layout [128][64] rows x shorts, key=(row&7)<<3 shorts):
// pass lanes 0-7 read rows r..r+7 same (kc,lhi) -> 8 distinct 16B slots ->
// all 32 banks; lanes 8-15 repeat = free 2-way. XOR bits 3-5 overlap
// kc*16 bits 4-5, so addr(ar,kc) = (base + ar*2048) ^ (kc*16) with
// base = l31*64 + (lhi*8 ^ key&8) + (key&0x30)  [bits 4-5 of base = key's,
// so ^kc*16 yields kc*16 ^ key&0x30; ar*2048 is bit 11, disjoint].
// ---------------------------------------------------------------------------
__global__ __launch_bounds__(512, 2) void k_gemm20(const __hip_bfloat16* __restrict__ Xb,
                                                   const __hip_bfloat16* __restrict__ Wb,
                                                   float* __restrict__ out) {
    __shared__ __align__(16) short L[2][2][2][8192];  // [buf][A/B][half][16KB]

    int bid = blockIdx.x;
    int swz = (bid & 7) * 128 + (bid >> 3);           // XCD-bijective (1024%8==0)
    int bn = swz & 15, bm = swz >> 4;
    int m0 = bm * 256, n0 = bn * 256;
    int t = threadIdx.x, lane = t & 63, wv = t >> 6;
    int wm = wv >> 2, wn = wv & 3, wnh = wn >> 1;

    // staging source (pre-swizzled, 3-bit XOR involution — r18-identical)
    int srow = t >> 3;
    int sko = ((t & 7) * 8) ^ (((t >> 3) & 7) * 8);
    const __hip_bfloat16* gA = Xb + (size_t)(m0 + srow) * K_TOTAL + sko;
    const __hip_bfloat16* gB = Wb + (size_t)(n0 + srow) * K_TOTAL + sko;

    auto stA = [&](int b, int h, int s_) {
        gload_lds16(gA + (size_t)(h * 128) * K_TOTAL + s_ * 64, &L[b][0][h][t * 8]);
        gload_lds16(gA + (size_t)(h * 128 + 64) * K_TOTAL + s_ * 64, &L[b][0][h][4096 + t * 8]);
    };
    auto stB = [&](int b, int h, int s_) {
        gload_lds16(gB + (size_t)(h * 128) * K_TOTAL + s_ * 64, &L[b][1][h][t * 8]);
        gload_lds16(gB + (size_t)(h * 128 + 64) * K_TOTAL + s_ * 64, &L[b][1][h][4096 + t * 8]);
    };

    // 32x32 frag-read lane constants
    const int l31 = lane & 31, lhi = lane >> 5;
    const int key = (l31 & 7) << 3;
    const int baseK = l31 * 64 + ((lhi * 8) ^ (key & 8)) + (key & 0x30);
    const int bco = (wn & 1) * 4096;

    f32x16 acc[4][2];
#pragma unroll
    for (int f = 0; f < 4; ++f)
#pragma unroll
        for (int j = 0; j < 2; ++j) acc[f][j] = (f32x16)(0.0f);

    bf16x8 Af[8], Bq0[4], Bq1[4];

    // reads: Af[u*4+kc] = A frag (ar=arb+u, kc); Bq[kc] = B frag (bc, kc)
#define RD_A2(arb) { _Pragma("unroll") for (int u = 0; u < 2; ++u) \
    _Pragma("unroll") for (int kc = 0; kc < 4; ++kc) \
        Af[u * 4 + kc] = *(const bf16x8*)&LA[(((arb) + u) * 2048 + baseK) ^ (kc * 16)]; }
#define RD_B(dst, bc) { _Pragma("unroll") for (int kc = 0; kc < 4; ++kc) \
        dst[kc] = *(const bf16x8*)&LB[((bco + (bc) * 2048) + baseK) ^ (kc * 16)]; }
#define MM8(arb, Bv, bc) { _Pragma("unroll") for (int kc = 0; kc < 4; ++kc) \
    _Pragma("unroll") for (int u = 0; u < 2; ++u) \
        acc[(arb) + u][bc] = __builtin_amdgcn_mfma_f32_32x32x16_bf16( \
            Af[u * 4 + kc], Bv[kc], acc[(arb) + u][bc], 0, 0, 0); }
#define BAR __builtin_amdgcn_s_barrier()
#define PRI(x) __builtin_amdgcn_s_setprio(x)
#define VMW(n) { asm volatile("s_waitcnt vmcnt(" #n ")" ::: "memory"); \
                 __builtin_amdgcn_sched_barrier(0); }

    // ---- prologue (r18-identical): b0 full (B then A), B(1)h0; VMW(2) ----
    stB(0, 0, 0); stB(0, 1, 0);
    stA(0, 0, 0); stA(0, 1, 0);
    stB(1, 0, 1);
    VMW(2);
    BAR;

    for (int i = 0; i < NSTEP / 2; ++i) {
        const int s = 2 * i;
        const bool g2 = (s + 2 < NSTEP);
        const bool g3 = (s + 3 < NSTEP);
        // ======== K-step s (buf 0) ========
        {
            const short* LA = &L[0][0][wm][0];
            const short* LB = &L[0][1][wnh][0];
            // p1
            RD_A2(0) RD_B(Bq0, 0)
            stB(1, 1, s + 1);
            BAR; PRI(1); MM8(0, Bq0, 0) PRI(0);
            // p2
            RD_B(Bq1, 1)
            stA(1, 0, s + 1);
            BAR; PRI(1); MM8(0, Bq1, 1) PRI(0);
            // p3
            RD_A2(2)
            stA(1, 1, s + 1);
            BAR; PRI(1); MM8(2, Bq0, 0) PRI(0);
            // p4
            if (g2) stB(0, 0, s + 2);
            BAR; PRI(1); MM8(2, Bq1, 1) PRI(0);
            if (g2) { VMW(2) } else { VMW(0) }
            BAR;
        }
        // ======== K-step s+1 (buf 1) ========
        {
            const short* LA = &L[1][0][wm][0];
            const short* LB = &L[1][1][wnh][0];
            // p5
            RD_A2(0) RD_B(Bq0, 0)
            if (g2) stB(0, 1, s + 2);
            BAR; PRI(1); MM8(0, Bq0, 0) PRI(0);
            // p6
            RD_B(Bq1, 1)
            if (g2) stA(0, 0, s + 2);
            BAR; PRI(1); MM8(0, Bq1, 1) PRI(0);
            // p7
            RD_A2(2)
            if (g2) stA(0, 1, s + 2);
            BAR; PRI(1); MM8(2, Bq0, 0) PRI(0);
            // p8
            if (g3) stB(1, 0, s + 3);
            BAR; PRI(1); MM8(2, Bq1, 1) PRI(0);
            if (i < NSTEP / 2 - 1) {
                if (g3) { VMW(2) } else { VMW(0) }
                BAR;
            }
        }
    }
#undef RD_A2
#undef RD_B
#undef MM8
#undef BAR
#undef PRI
#undef VMW

    // ---- epilogue: C/D col=lane&31, row=(reg&3)+8*(reg>>2)+4*(lane>>5) ----
#pragma unroll
    for (int f = 0; f < 4; ++f)
#pragma unroll
        for (int j = 0; j < 2; ++j) {
            f32x16 v = acc[f][j];
            int c = n0 + wn * 64 + j * 32 + l31;
            int rbase = m0 + wm * 128 + f * 32 + 4 * lhi;
#pragma unroll
            for (int gq = 0; gq < 4; ++gq)
#pragma unroll
                for (int q = 0; q < 4; ++q)
                    out[(size_t)(rbase + 8 * gq + q) * N_TOTAL + c] = v[gq * 4 + q];
        }
}

// ---------------------------------------------------------------------------
// Tier B: m97-structure GEMM, A reg-staged from f32 X (round-5 verified).
// ---------------------------------------------------------------------------
__global__ __launch_bounds__(256) void k_gemm2b(const float* __restrict__ X,
                                                const __hip_bfloat16* __restrict__ Wb,
                                                float* __restrict__ out) {
    __shared__ __align__(16) short As[128 * 32];
    __shared__ __align__(16) short Bs[128 * 32];
    int bid = blockIdx.x;
    int swz = (bid & 7) * 512 + (bid >> 3);
    int bn = swz & 31, bm = swz >> 5;
    int m0 = bm * 128, n0 = bn * 128;
    int t = threadIdx.x, lane = t & 63, wv = t >> 6;
    int wr = wv >> 1, wc = wv & 1;
    f32x4 acc[4][4];
#pragma unroll
    for (int i = 0; i < 4; ++i)
#pragma unroll
        for (int j = 0; j < 4; ++j) acc[i][j] = (f32x4)(0.0f);
    int arow = t >> 2, acol = (t & 3) * 8;
    const float* Agf0 = X + (size_t)(m0 + arow) * K_TOTAL + acol;
    const float* Agf1 = Agf0 + (size_t)64 * K_TOTAL;
    const __hip_bfloat16* Bg0 = Wb + (size_t)(n0 + arow) * K_TOTAL + acol;
    const __hip_bfloat16* Bg1 = Bg0 + (size_t)64 * K_TOTAL;
    float4 xa0 = *(const float4*)(Agf0), xa1 = *(const float4*)(Agf0 + 4);
    float4 xb0 = *(const float4*)(Agf1), xb1 = *(const float4*)(Agf1 + 4);
    for (int kt = 0; kt < NT32; ++kt) {
        if (kt) __syncthreads();
        __hip_bfloat162 oa[4] = {
            __float22bfloat162_rn(make_float2(xa0.x, xa0.y)),
            __float22bfloat162_rn(make_float2(xa0.z, xa0.w)),
            __float22bfloat162_rn(make_float2(xa1.x, xa1.y)),
            __float22bfloat162_rn(make_float2(xa1.z, xa1.w))};
        __hip_bfloat162 ob[4] = {
            __float22bfloat162_rn(make_float2(xb0.x, xb0.y)),
            __float22bfloat162_rn(make_float2(xb0.z, xb0.w)),
            __float22bfloat162_rn(make_float2(xb1.x, xb1.y)),
            __float22bfloat162_rn(make_float2(xb1.z, xb1.w))};
        *(int4*)&As[t * 8] = *(int4*)&oa[0];
        *(int4*)&As[2048 + t * 8] = *(int4*)&ob[0];
        gload_lds16(Bg0 + kt * 32, &Bs[t * 8]);
        gload_lds16(Bg1 + kt * 32, &Bs[2048 + t * 8]);
        __syncthreads();
        if (kt < NT32 - 1) {
            int ko = (kt + 1) * 32;
            xa0 = *(const float4*)(Agf0 + ko);
            xa1 = *(const float4*)(Agf0 + ko + 4);
            xb0 = *(const float4*)(Agf1 + ko);
            xb1 = *(const float4*)(Agf1 + ko + 4);
        }
        bf16x8 a[4], b[4];
        int ro = (lane & 15) * 32 + (lane >> 4) * 8;
#pragma unroll
        for (int i = 0; i < 4; ++i)
            a[i] = *(const bf16x8*)&As[(wr * 64 + i * 16) * 32 + ro];
#pragma unroll
        for (int j = 0; j < 4; ++j)
            b[j] = *(const bf16x8*)&Bs[(wc * 64 + j * 16) * 32 + ro];
#pragma unroll
        for (int i = 0; i < 4; ++i)
#pragma unroll
            for (int j = 0; j < 4; ++j)
                acc[i][j] = __builtin_amdgcn_mfma_f32_16x16x32_bf16(a[i], b[j], acc[i][j], 0, 0, 0);
    }
    int col0 = n0 + wc * 64 + (lane & 15);
    int row0 = m0 + wr * 64 + (lane >> 4) * 4;
#pragma unroll
    for (int i = 0; i < 4; ++i)
#pragma unroll
        for (int j = 0; j < 4; ++j) {
            f32x4 v = acc[i][j];
            int r = row0 + i * 16, c = col0 + j * 16;
#pragma unroll
            for (int q = 0; q < 4; ++q)
                out[(size_t)(r + q) * N_TOTAL + c] = v[q];
        }
}

extern "C" void kernel_launch(void* const* d_in, const int* in_sizes, int n_in,
                              void* d_out, int out_size, void* d_ws, size_t ws_size,
                              hipStream_t stream) {
    const float* X = (const float*)d_in[0];
    const int* PW = (const int*)d_in[1];
    const float* SC = (const float*)d_in[2];
    float* OUT = (float*)d_out;

    const size_t needW = (size_t)N_TOTAL * K_TOTAL * 2;            // 33.5 MB
    const size_t needX = needW + (size_t)M_TOTAL * K_TOTAL * 2;    // +134 MB

    if (ws_size >= needX) {
        __hip_bfloat16* Wb = (__hip_bfloat16*)d_ws;
        __hip_bfloat16* Xb = (__hip_bfloat16*)((char*)d_ws + needW);
        k_convX<<<dim3(32768), dim3(256), 0, stream>>>(X, Xb);
        k_dequant<<<dim3(4096), dim3(256), 0, stream>>>(PW, SC, Wb);
        k_gemm20<<<dim3((M_TOTAL / 256) * (N_TOTAL / 256)), dim3(512), 0, stream>>>(Xb, Wb, OUT);
    } else if (ws_size >= needW) {
        __hip_bfloat16* Wb = (__hip_bfloat16*)d_ws;
        k_dequant<<<dim3(4096), dim3(256), 0, stream>>>(PW, SC, Wb);
        k_gemm2b<<<dim3((M_TOTAL / 128) * (N_TOTAL / 128)), dim3(256), 0, stream>>>(X, Wb, OUT);
    }
}

// Round 21
// 539.919 us; speedup vs baseline: 1.1032x; 1.1032x over previous
//
#include <hip/hip_runtime.h>
#include <hip/hip_bf16.h>
#include <stdint.h>

#define M_TOTAL 16384
#define N_TOTAL 4096
#define K_TOTAL 4096
#define NSTEP (K_TOTAL / 64)   // 64 K-steps of 64
#define NT32 (K_TOTAL / 32)

typedef __attribute__((ext_vector_type(8))) short bf16x8;
typedef __attribute__((ext_vector_type(4))) float f32x4;

__device__ __forceinline__ void gload_lds16(const void* g, void* l) {
    __builtin_amdgcn_global_load_lds(
        (const __attribute__((address_space(1))) uint32_t*)g,
        (__attribute__((address_space(3))) uint32_t*)l, 16, 0, 0);
}

// ---------------------------------------------------------------------------
// Kernel 0: X f32 -> bf16.
// ---------------------------------------------------------------------------
__global__ __launch_bounds__(256) void k_convX(const float* __restrict__ X,
                                               __hip_bfloat16* __restrict__ Xb) {
    size_t t = (size_t)blockIdx.x * 256 + threadIdx.x;
    const float* p = X + t * 8;
    float4 a = *(const float4*)p;
    float4 b = *(const float4*)(p + 4);
    __hip_bfloat162 o[4] = {
        __float22bfloat162_rn(make_float2(a.x, a.y)),
        __float22bfloat162_rn(make_float2(a.z, a.w)),
        __float22bfloat162_rn(make_float2(b.x, b.y)),
        __float22bfloat162_rn(make_float2(b.z, b.w))};
    *(int4*)(Xb + t * 8) = *(int4*)&o[0];
}

// ---------------------------------------------------------------------------
// Kernel 1: packed int4 -> bf16 W[N][K].
// ---------------------------------------------------------------------------
__global__ __launch_bounds__(256) void k_dequant(const int* __restrict__ pw,
                                                 const float* __restrict__ sc,
                                                 __hip_bfloat16* __restrict__ W) {
    int t = blockIdx.x * 256 + threadIdx.x;
    int row = t >> 8;
    int w0 = (t & 255) << 3;
    const int* p = pw + (size_t)row * 2048 + w0;
    int4 q0 = *(const int4*)p;
    int4 q1 = *(const int4*)(p + 4);
    float s = sc[row * 128 + (w0 >> 4)];
    float ns8 = -8.0f * s;
    int w[8] = {q0.x, q0.y, q0.z, q0.w, q1.x, q1.y, q1.z, q1.w};
    __hip_bfloat162 o[8];
#pragma unroll
    for (int i = 0; i < 8; ++i) {
        float lo = fmaf((float)(w[i] & 15), s, ns8);
        float hi = fmaf((float)(w[i] >> 4), s, ns8);
        o[i] = __float22bfloat162_rn(make_float2(lo, hi));
    }
    __hip_bfloat16* dst = W + (size_t)row * 4096 + w0 * 2;
    *(int4*)dst = *(int4*)&o[0];
    *(int4*)(dst + 8) = *(int4*)&o[4];
}

// ---------------------------------------------------------------------------
// Kernel 2 (tier A): r18 (single-barrier 8-phase, row-major + 3-bit XOR,
// 16x16x32 MFMA — all verified) with a DEEPER STAGE ROTATION. Only change:
// stage-call placement. Region-lifetime audit (stage at p legal if region's
// last read consumed by MFMA(p-2); single-barrier rule):
//   buf1.A last read p7' (consumed MFMA(p7')) -> stage legal at p1
//   buf1.B-h1 last read p6' -> p1;  buf0.B-h0/h1 last read p2 -> p4/p5
//   buf0.A last read p3 -> p5
// Rotation: p1: A(s+1)h0, A(s+1)h1, B(s+1)h1 (6 gloads)
//           p4: B(s+2)h0 (2)   p5: A(s+2)h0, A(s+2)h1, B(s+2)h1 (6)
//           p8: B(s+3)h0 (2)
// Ledger (10 outstanding at each wait): p4-end VMW(2) drains [B(s+1)h0
// (p8', 4-phase-old), p1's 6 (3-phase)] = tile s+1 ✓, leaves B(s+2)h0.
// p8-end VMW(2) drains [p4's 2 (4-phase), p5's 6 (3-phase)] = tile s+2 ✓.
// Every waited load >= 3 phases (~1600cy) in flight > ~900cy HBM latency
// -> VMW stalls (~2x350cy/step in r18, where A(s+1)h1 had 1-phase depth)
// eliminated. Last iter: p1 stages tile 63; VMW(0) at p4; nothing after.
// ---------------------------------------------------------------------------
__global__ __launch_bounds__(512, 2) void k_gemm21(const __hip_bfloat16* __restrict__ Xb,
                                                   const __hip_bfloat16* __restrict__ Wb,
                                                   float* __restrict__ out) {
    __shared__ __align__(16) short L[2][2][2][8192];  // [buf][A/B][half][16KB]

    int bid = blockIdx.x;
    int swz = (bid & 7) * 128 + (bid >> 3);           // XCD-bijective (1024%8==0)
    int bn = swz & 15, bm = swz >> 4;
    int m0 = bm * 256, n0 = bn * 256;
    int t = threadIdx.x, lane = t & 63, wv = t >> 6;
    int wm = wv >> 2, wn = wv & 3, wnh = wn >> 1;

    // staging source (pre-swizzled, 3-bit XOR involution — r16/r18-verified)
    int srow = t >> 3;
    int sko = ((t & 7) * 8) ^ (((t >> 3) & 7) * 8);
    const __hip_bfloat16* gA = Xb + (size_t)(m0 + srow) * K_TOTAL + sko;
    const __hip_bfloat16* gB = Wb + (size_t)(n0 + srow) * K_TOTAL + sko;

    auto stA = [&](int b, int h, int s_) {
        gload_lds16(gA + (size_t)(h * 128) * K_TOTAL + s_ * 64, &L[b][0][h][t * 8]);
        gload_lds16(gA + (size_t)(h * 128 + 64) * K_TOTAL + s_ * 64, &L[b][0][h][4096 + t * 8]);
    };
    auto stB = [&](int b, int h, int s_) {
        gload_lds16(gB + (size_t)(h * 128) * K_TOTAL + s_ * 64, &L[b][1][h][t * 8]);
        gload_lds16(gB + (size_t)(h * 128 + 64) * K_TOTAL + s_ * 64, &L[b][1][h][4096 + t * 8]);
    };

    // frag-read lane constants (3-bit XOR, r16-verified 0-conflict)
    const int l15 = lane & 15;
    const int kb = (lane >> 4) * 8;
    const int kx = kb ^ ((l15 & 7) << 3);
    const int roff = l15 * 64 + kx;
    const int roff2 = roff ^ 32;
    const int bco = (wn & 1) * 4096;

    f32x4 acc[8][4];
#pragma unroll
    for (int f = 0; f < 8; ++f)
#pragma unroll
        for (int j = 0; j < 4; ++j) acc[f][j] = (f32x4)(0.0f);

    bf16x8 Af[8], Bq01[4], Bq23[4];

#define RD_A(rfb) { _Pragma("unroll") for (int rf = 0; rf < 4; ++rf) { \
        Af[rf * 2]     = *(const bf16x8*)&LA[((rfb) + rf) * 1024 + roff]; \
        Af[rf * 2 + 1] = *(const bf16x8*)&LA[((rfb) + rf) * 1024 + roff2]; } }
#define RD_B(dst, cfb) { _Pragma("unroll") for (int cf = 0; cf < 2; ++cf) { \
        dst[cf * 2]     = *(const bf16x8*)&LB[bco + ((cfb) + cf) * 1024 + roff]; \
        dst[cf * 2 + 1] = *(const bf16x8*)&LB[bco + ((cfb) + cf) * 1024 + roff2]; } }
#define MM16(rfb, Bv, cfb) { _Pragma("unroll") for (int kk = 0; kk < 2; ++kk) \
        _Pragma("unroll") for (int rf = 0; rf < 4; ++rf) \
        _Pragma("unroll") for (int cf = 0; cf < 2; ++cf) \
            acc[(rfb) + rf][(cfb) + cf] = __builtin_amdgcn_mfma_f32_16x16x32_bf16( \
                Af[rf * 2 + kk], Bv[cf * 2 + kk], acc[(rfb) + rf][(cfb) + cf], 0, 0, 0); }
#define BAR __builtin_amdgcn_s_barrier()
#define PRI(x) __builtin_amdgcn_s_setprio(x)
#define VMW(n) { asm volatile("s_waitcnt vmcnt(" #n ")" ::: "memory"); \
                 __builtin_amdgcn_sched_barrier(0); }

    // ---- prologue (r18-identical): b0 full (B then A), B(1)h0; VMW(2) ----
    stB(0, 0, 0); stB(0, 1, 0);
    stA(0, 0, 0); stA(0, 1, 0);
    stB(1, 0, 1);
    VMW(2);
    BAR;

    for (int i = 0; i < NSTEP / 2; ++i) {
        const int s = 2 * i;
        const bool lastI = (i == NSTEP / 2 - 1);
        // ======== K-step s (buf 0) ========
        {
            const short* LA = &L[0][0][wm][0];
            const short* LB = &L[0][1][wnh][0];
            // p1: all remaining tile-(s+1) stages (regions consumed by p6'/p7')
            RD_A(0) RD_B(Bq01, 0)
            stA(1, 0, s + 1);
            stA(1, 1, s + 1);
            stB(1, 1, s + 1);
            BAR; PRI(1); MM16(0, Bq01, 0) PRI(0);
            // p2
            RD_B(Bq23, 2)
            BAR; PRI(1); MM16(0, Bq23, 2) PRI(0);
            // p3
            RD_A(4)
            BAR; PRI(1); MM16(4, Bq01, 0) PRI(0);
            // p4
            if (!lastI) stB(0, 0, s + 2);
            BAR; PRI(1); MM16(4, Bq23, 2) PRI(0);
            if (!lastI) { VMW(2) } else { VMW(0) }
            BAR;
        }
        // ======== K-step s+1 (buf 1) ========
        {
            const short* LA = &L[1][0][wm][0];
            const short* LB = &L[1][1][wnh][0];
            // p5: all remaining tile-(s+2) stages (buf0 regions consumed p2/p3)
            RD_A(0) RD_B(Bq01, 0)
            if (!lastI) {
                stA(0, 0, s + 2);
                stA(0, 1, s + 2);
                stB(0, 1, s + 2);
            }
            BAR; PRI(1); MM16(0, Bq01, 0) PRI(0);
            // p6
            RD_B(Bq23, 2)
            BAR; PRI(1); MM16(0, Bq23, 2) PRI(0);
            // p7
            RD_A(4)
            BAR; PRI(1); MM16(4, Bq01, 0) PRI(0);
            // p8
            if (!lastI) stB(1, 0, s + 3);
            BAR; PRI(1); MM16(4, Bq23, 2) PRI(0);
            if (!lastI) {
                VMW(2)
                BAR;
            }
        }
    }
#undef RD_A
#undef RD_B
#undef MM16
#undef BAR
#undef PRI
#undef VMW

    // ---- epilogue: C/D layout col=lane&15, row=(lane>>4)*4+reg ----
    int col0 = n0 + wn * 64 + l15;
    int row0 = m0 + wm * 128 + (lane >> 4) * 4;
#pragma unroll
    for (int f = 0; f < 8; ++f)
#pragma unroll
        for (int j = 0; j < 4; ++j) {
            f32x4 v = acc[f][j];
            int r = row0 + f * 16;
            int c = col0 + j * 16;
#pragma unroll
            for (int q = 0; q < 4; ++q)
                out[(size_t)(r + q) * N_TOTAL + c] = v[q];
        }
}

// ---------------------------------------------------------------------------
// Tier B: m97-structure GEMM, A reg-staged from f32 X (round-5 verified).
// ---------------------------------------------------------------------------
__global__ __launch_bounds__(256) void k_gemm2b(const float* __restrict__ X,
                                                const __hip_bfloat16* __restrict__ Wb,
                                                float* __restrict__ out) {
    __shared__ __align__(16) short As[128 * 32];
    __shared__ __align__(16) short Bs[128 * 32];
    int bid = blockIdx.x;
    int swz = (bid & 7) * 512 + (bid >> 3);
    int bn = swz & 31, bm = swz >> 5;
    int m0 = bm * 128, n0 = bn * 128;
    int t = threadIdx.x, lane = t & 63, wv = t >> 6;
    int wr = wv >> 1, wc = wv & 1;
    f32x4 acc[4][4];
#pragma unroll
    for (int i = 0; i < 4; ++i)
#pragma unroll
        for (int j = 0; j < 4; ++j) acc[i][j] = (f32x4)(0.0f);
    int arow = t >> 2, acol = (t & 3) * 8;
    const float* Agf0 = X + (size_t)(m0 + arow) * K_TOTAL + acol;
    const float* Agf1 = Agf0 + (size_t)64 * K_TOTAL;
    const __hip_bfloat16* Bg0 = Wb + (size_t)(n0 + arow) * K_TOTAL + acol;
    const __hip_bfloat16* Bg1 = Bg0 + (size_t)64 * K_TOTAL;
    float4 xa0 = *(const float4*)(Agf0), xa1 = *(const float4*)(Agf0 + 4);
    float4 xb0 = *(const float4*)(Agf1), xb1 = *(const float4*)(Agf1 + 4);
    for (int kt = 0; kt < NT32; ++kt) {
        if (kt) __syncthreads();
        __hip_bfloat162 oa[4] = {
            __float22bfloat162_rn(make_float2(xa0.x, xa0.y)),
            __float22bfloat162_rn(make_float2(xa0.z, xa0.w)),
            __float22bfloat162_rn(make_float2(xa1.x, xa1.y)),
            __float22bfloat162_rn(make_float2(xa1.z, xa1.w))};
        __hip_bfloat162 ob[4] = {
            __float22bfloat162_rn(make_float2(xb0.x, xb0.y)),
            __float22bfloat162_rn(make_float2(xb0.z, xb0.w)),
            __float22bfloat162_rn(make_float2(xb1.x, xb1.y)),
            __float22bfloat162_rn(make_float2(xb1.z, xb1.w))};
        *(int4*)&As[t * 8] = *(int4*)&oa[0];
        *(int4*)&As[2048 + t * 8] = *(int4*)&ob[0];
        gload_lds16(Bg0 + kt * 32, &Bs[t * 8]);
        gload_lds16(Bg1 + kt * 32, &Bs[2048 + t * 8]);
        __syncthreads();
        if (kt < NT32 - 1) {
            int ko = (kt + 1) * 32;
            xa0 = *(const float4*)(Agf0 + ko);
            xa1 = *(const float4*)(Agf0 + ko + 4);
            xb0 = *(const float4*)(Agf1 + ko);
            xb1 = *(const float4*)(Agf1 + ko + 4);
        }
        bf16x8 a[4], b[4];
        int ro = (lane & 15) * 32 + (lane >> 4) * 8;
#pragma unroll
        for (int i = 0; i < 4; ++i)
            a[i] = *(const bf16x8*)&As[(wr * 64 + i * 16) * 32 + ro];
#pragma unroll
        for (int j = 0; j < 4; ++j)
            b[j] = *(const bf16x8*)&Bs[(wc * 64 + j * 16) * 32 + ro];
#pragma unroll
        for (int i = 0; i < 4; ++i)
#pragma unroll
            for (int j = 0; j < 4; ++j)
                acc[i][j] = __builtin_amdgcn_mfma_f32_16x16x32_bf16(a[i], b[j], acc[i][j], 0, 0, 0);
    }
    int col0 = n0 + wc * 64 + (lane & 15);
    int row0 = m0 + wr * 64 + (lane >> 4) * 4;
#pragma unroll
    for (int i = 0; i < 4; ++i)
#pragma unroll
        for (int j = 0; j < 4; ++j) {
            f32x4 v = acc[i][j];
            int r = row0 + i * 16, c = col0 + j * 16;
#pragma unroll
            for (int q = 0; q < 4; ++q)
                out[(size_t)(r + q) * N_TOTAL + c] = v[q];
        }
}

extern "C" void kernel_launch(void* const* d_in, const int* in_sizes, int n_in,
                              void* d_out, int out_size, void* d_ws, size_t ws_size,
                              hipStream_t stream) {
    const float* X = (const float*)d_in[0];
    const int* PW = (const int*)d_in[1];
    const float* SC = (const float*)d_in[2];
    float* OUT = (float*)d_out;

    const size_t needW = (size_t)N_TOTAL * K_TOTAL * 2;            // 33.5 MB
    const size_t needX = needW + (size_t)M_TOTAL * K_TOTAL * 2;    // +134 MB

    if (ws_size >= needX) {
        __hip_bfloat16* Wb = (__hip_bfloat16*)d_ws;
        __hip_bfloat16* Xb = (__hip_bfloat16*)((char*)d_ws + needW);
        k_convX<<<dim3(32768), dim3(256), 0, stream>>>(X, Xb);
        k_dequant<<<dim3(4096), dim3(256), 0, stream>>>(PW, SC, Wb);
        k_gemm21<<<dim3((M_TOTAL / 256) * (N_TOTAL / 256)), dim3(512), 0, stream>>>(Xb, Wb, OUT);
    } else if (ws_size >= needW) {
        __hip_bfloat16* Wb = (__hip_bfloat16*)d_ws;
        k_dequant<<<dim3(4096), dim3(256), 0, stream>>>(PW, SC, Wb);
        k_gemm2b<<<dim3((M_TOTAL / 128) * (N_TOTAL / 128)), dim3(256), 0, stream>>>(X, Wb, OUT);
    }
}

// Round 22
// 532.394 us; speedup vs baseline: 1.1188x; 1.0141x over previous
//
#include <hip/hip_runtime.h>
#include <hip/hip_bf16.h>
#include <stdint.h>

#define M_TOTAL 16384
#define N_TOTAL 4096
#define K_TOTAL 4096
#define NSTEP (K_TOTAL / 64)   // 64 K-steps of 64
#define NT32 (K_TOTAL / 32)

typedef __attribute__((ext_vector_type(8))) short bf16x8;
typedef __attribute__((ext_vector_type(4))) float f32x4;

__device__ __forceinline__ void gload_lds16(const void* g, void* l) {
    __builtin_amdgcn_global_load_lds(
        (const __attribute__((address_space(1))) uint32_t*)g,
        (__attribute__((address_space(3))) uint32_t*)l, 16, 0, 0);
}

// ---------------------------------------------------------------------------
// Kernel 0: X f32 -> bf16.
// ---------------------------------------------------------------------------
__global__ __launch_bounds__(256) void k_convX(const float* __restrict__ X,
                                               __hip_bfloat16* __restrict__ Xb) {
    size_t t = (size_t)blockIdx.x * 256 + threadIdx.x;
    const float* p = X + t * 8;
    float4 a = *(const float4*)p;
    float4 b = *(const float4*)(p + 4);
    __hip_bfloat162 o[4] = {
        __float22bfloat162_rn(make_float2(a.x, a.y)),
        __float22bfloat162_rn(make_float2(a.z, a.w)),
        __float22bfloat162_rn(make_float2(b.x, b.y)),
        __float22bfloat162_rn(make_float2(b.z, b.w))};
    *(int4*)(Xb + t * 8) = *(int4*)&o[0];
}

// ---------------------------------------------------------------------------
// Kernel 1: packed int4 -> bf16 W[N][K].
// ---------------------------------------------------------------------------
__global__ __launch_bounds__(256) void k_dequant(const int* __restrict__ pw,
                                                 const float* __restrict__ sc,
                                                 __hip_bfloat16* __restrict__ W) {
    int t = blockIdx.x * 256 + threadIdx.x;
    int row = t >> 8;
    int w0 = (t & 255) << 3;
    const int* p = pw + (size_t)row * 2048 + w0;
    int4 q0 = *(const int4*)p;
    int4 q1 = *(const int4*)(p + 4);
    float s = sc[row * 128 + (w0 >> 4)];
    float ns8 = -8.0f * s;
    int w[8] = {q0.x, q0.y, q0.z, q0.w, q1.x, q1.y, q1.z, q1.w};
    __hip_bfloat162 o[8];
#pragma unroll
    for (int i = 0; i < 8; ++i) {
        float lo = fmaf((float)(w[i] & 15), s, ns8);
        float hi = fmaf((float)(w[i] >> 4), s, ns8);
        o[i] = __float22bfloat162_rn(make_float2(lo, hi));
    }
    __hip_bfloat16* dst = W + (size_t)row * 4096 + w0 * 2;
    *(int4*)dst = *(int4*)&o[0];
    *(int4*)(dst + 8) = *(int4*)&o[4];
}

// ---------------------------------------------------------------------------
// Kernel 2 (tier A): r18 champion (single-barrier 8-phase, r9 stage rotation
// + VMW(2) ledger, row-major + full 3-bit XOR layout, 16x16x32 MFMA) plus
// the m201 template's PRE-BARRIER PARTIAL LGKM DRAIN: after heavy read
// groups, `s_waitcnt lgkmcnt(4)` before the barrier pulls read-service into
// the barrier-stagger window instead of the post-barrier MFMA head.
// Safety: an extra wait cannot race; compiler's own conservative counted
// lgkm waits (it cannot parse inline asm) remain on top.
// ---------------------------------------------------------------------------
__global__ __launch_bounds__(512, 2) void k_gemm22(const __hip_bfloat16* __restrict__ Xb,
                                                   const __hip_bfloat16* __restrict__ Wb,
                                                   float* __restrict__ out) {
    __shared__ __align__(16) short L[2][2][2][8192];  // [buf][A/B][half][16KB]

    int bid = blockIdx.x;
    int swz = (bid & 7) * 128 + (bid >> 3);           // XCD-bijective (1024%8==0)
    int bn = swz & 15, bm = swz >> 4;
    int m0 = bm * 256, n0 = bn * 256;
    int t = threadIdx.x, lane = t & 63, wv = t >> 6;
    int wm = wv >> 2, wn = wv & 3, wnh = wn >> 1;

    // staging source (pre-swizzled, 3-bit XOR involution — r16/r18-verified)
    int srow = t >> 3;
    int sko = ((t & 7) * 8) ^ (((t >> 3) & 7) * 8);
    const __hip_bfloat16* gA = Xb + (size_t)(m0 + srow) * K_TOTAL + sko;
    const __hip_bfloat16* gB = Wb + (size_t)(n0 + srow) * K_TOTAL + sko;

    auto stA = [&](int b, int h, int s_) {
        gload_lds16(gA + (size_t)(h * 128) * K_TOTAL + s_ * 64, &L[b][0][h][t * 8]);
        gload_lds16(gA + (size_t)(h * 128 + 64) * K_TOTAL + s_ * 64, &L[b][0][h][4096 + t * 8]);
    };
    auto stB = [&](int b, int h, int s_) {
        gload_lds16(gB + (size_t)(h * 128) * K_TOTAL + s_ * 64, &L[b][1][h][t * 8]);
        gload_lds16(gB + (size_t)(h * 128 + 64) * K_TOTAL + s_ * 64, &L[b][1][h][4096 + t * 8]);
    };

    // frag-read lane constants (3-bit XOR, r16-verified 0-conflict)
    const int l15 = lane & 15;
    const int kb = (lane >> 4) * 8;
    const int kx = kb ^ ((l15 & 7) << 3);
    const int roff = l15 * 64 + kx;
    const int roff2 = roff ^ 32;
    const int bco = (wn & 1) * 4096;

    f32x4 acc[8][4];
#pragma unroll
    for (int f = 0; f < 8; ++f)
#pragma unroll
        for (int j = 0; j < 4; ++j) acc[f][j] = (f32x4)(0.0f);

    bf16x8 Af[8], Bq01[4], Bq23[4];

#define RD_A(rfb) { _Pragma("unroll") for (int rf = 0; rf < 4; ++rf) { \
        Af[rf * 2]     = *(const bf16x8*)&LA[((rfb) + rf) * 1024 + roff]; \
        Af[rf * 2 + 1] = *(const bf16x8*)&LA[((rfb) + rf) * 1024 + roff2]; } }
#define RD_B(dst, cfb) { _Pragma("unroll") for (int cf = 0; cf < 2; ++cf) { \
        dst[cf * 2]     = *(const bf16x8*)&LB[bco + ((cfb) + cf) * 1024 + roff]; \
        dst[cf * 2 + 1] = *(const bf16x8*)&LB[bco + ((cfb) + cf) * 1024 + roff2]; } }
#define MM16(rfb, Bv, cfb) { _Pragma("unroll") for (int kk = 0; kk < 2; ++kk) \
        _Pragma("unroll") for (int rf = 0; rf < 4; ++rf) \
        _Pragma("unroll") for (int cf = 0; cf < 2; ++cf) \
            acc[(rfb) + rf][(cfb) + cf] = __builtin_amdgcn_mfma_f32_16x16x32_bf16( \
                Af[rf * 2 + kk], Bv[cf * 2 + kk], acc[(rfb) + rf][(cfb) + cf], 0, 0, 0); }
#define BAR __builtin_amdgcn_s_barrier()
#define PRI(x) __builtin_amdgcn_s_setprio(x)
#define VMW(n) { asm volatile("s_waitcnt vmcnt(" #n ")" ::: "memory"); \
                 __builtin_amdgcn_sched_barrier(0); }
#define LKH(n) { asm volatile("s_waitcnt lgkmcnt(" #n ")"); \
                 __builtin_amdgcn_sched_barrier(0); }

    // ---- prologue (r18-identical): b0 full (B then A), B(1)h0; VMW(2) ----
    stB(0, 0, 0); stB(0, 1, 0);
    stA(0, 0, 0); stA(0, 1, 0);
    stB(1, 0, 1);
    VMW(2);
    BAR;

    for (int i = 0; i < NSTEP / 2; ++i) {
        const int s = 2 * i;
        const bool g2 = (s + 2 < NSTEP);
        const bool g3 = (s + 3 < NSTEP);
        // ======== K-step s (buf 0) ========
        {
            const short* LA = &L[0][0][wm][0];
            const short* LB = &L[0][1][wnh][0];
            // p1 (12 reads -> pre-drain to 4 before BAR)
            RD_A(0) RD_B(Bq01, 0)
            stB(1, 1, s + 1);
            LKH(4);
            BAR; PRI(1); MM16(0, Bq01, 0) PRI(0);
            // p2 (4 reads)
            RD_B(Bq23, 2)
            stA(1, 0, s + 1);
            BAR; PRI(1); MM16(0, Bq23, 2) PRI(0);
            // p3 (8 reads -> pre-drain to 4)
            RD_A(4)
            stA(1, 1, s + 1);
            LKH(4);
            BAR; PRI(1); MM16(4, Bq01, 0) PRI(0);
            // p4
            if (g2) stB(0, 0, s + 2);
            BAR; PRI(1); MM16(4, Bq23, 2) PRI(0);
            if (g2) { VMW(2) } else { VMW(0) }
            BAR;
        }
        // ======== K-step s+1 (buf 1) ========
        {
            const short* LA = &L[1][0][wm][0];
            const short* LB = &L[1][1][wnh][0];
            // p5 (12 reads -> pre-drain to 4)
            RD_A(0) RD_B(Bq01, 0)
            if (g2) stB(0, 1, s + 2);
            LKH(4);
            BAR; PRI(1); MM16(0, Bq01, 0) PRI(0);
            // p6 (4 reads)
            RD_B(Bq23, 2)
            if (g2) stA(0, 0, s + 2);
            BAR; PRI(1); MM16(0, Bq23, 2) PRI(0);
            // p7 (8 reads -> pre-drain to 4)
            RD_A(4)
            if (g2) stA(0, 1, s + 2);
            LKH(4);
            BAR; PRI(1); MM16(4, Bq01, 0) PRI(0);
            // p8
            if (g3) stB(1, 0, s + 3);
            BAR; PRI(1); MM16(4, Bq23, 2) PRI(0);
            if (i < NSTEP / 2 - 1) {
                if (g3) { VMW(2) } else { VMW(0) }
                BAR;
            }
        }
    }
#undef RD_A
#undef RD_B
#undef MM16
#undef BAR
#undef PRI
#undef VMW
#undef LKH

    // ---- epilogue: C/D layout col=lane&15, row=(lane>>4)*4+reg ----
    int col0 = n0 + wn * 64 + l15;
    int row0 = m0 + wm * 128 + (lane >> 4) * 4;
#pragma unroll
    for (int f = 0; f < 8; ++f)
#pragma unroll
        for (int j = 0; j < 4; ++j) {
            f32x4 v = acc[f][j];
            int r = row0 + f * 16;
            int c = col0 + j * 16;
#pragma unroll
            for (int q = 0; q < 4; ++q)
                out[(size_t)(r + q) * N_TOTAL + c] = v[q];
        }
}

// ---------------------------------------------------------------------------
// Tier B: m97-structure GEMM, A reg-staged from f32 X (round-5 verified).
// ---------------------------------------------------------------------------
__global__ __launch_bounds__(256) void k_gemm2b(const float* __restrict__ X,
                                                const __hip_bfloat16* __restrict__ Wb,
                                                float* __restrict__ out) {
    __shared__ __align__(16) short As[128 * 32];
    __shared__ __align__(16) short Bs[128 * 32];
    int bid = blockIdx.x;
    int swz = (bid & 7) * 512 + (bid >> 3);
    int bn = swz & 31, bm = swz >> 5;
    int m0 = bm * 128, n0 = bn * 128;
    int t = threadIdx.x, lane = t & 63, wv = t >> 6;
    int wr = wv >> 1, wc = wv & 1;
    f32x4 acc[4][4];
#pragma unroll
    for (int i = 0; i < 4; ++i)
#pragma unroll
        for (int j = 0; j < 4; ++j) acc[i][j] = (f32x4)(0.0f);
    int arow = t >> 2, acol = (t & 3) * 8;
    const float* Agf0 = X + (size_t)(m0 + arow) * K_TOTAL + acol;
    const float* Agf1 = Agf0 + (size_t)64 * K_TOTAL;
    const __hip_bfloat16* Bg0 = Wb + (size_t)(n0 + arow) * K_TOTAL + acol;
    const __hip_bfloat16* Bg1 = Bg0 + (size_t)64 * K_TOTAL;
    float4 xa0 = *(const float4*)(Agf0), xa1 = *(const float4*)(Agf0 + 4);
    float4 xb0 = *(const float4*)(Agf1), xb1 = *(const float4*)(Agf1 + 4);
    for (int kt = 0; kt < NT32; ++kt) {
        if (kt) __syncthreads();
        __hip_bfloat162 oa[4] = {
            __float22bfloat162_rn(make_float2(xa0.x, xa0.y)),
            __float22bfloat162_rn(make_float2(xa0.z, xa0.w)),
            __float22bfloat162_rn(make_float2(xa1.x, xa1.y)),
            __float22bfloat162_rn(make_float2(xa1.z, xa1.w))};
        __hip_bfloat162 ob[4] = {
            __float22bfloat162_rn(make_float2(xb0.x, xb0.y)),
            __float22bfloat162_rn(make_float2(xb0.z, xb0.w)),
            __float22bfloat162_rn(make_float2(xb1.x, xb1.y)),
            __float22bfloat162_rn(make_float2(xb1.z, xb1.w))};
        *(int4*)&As[t * 8] = *(int4*)&oa[0];
        *(int4*)&As[2048 + t * 8] = *(int4*)&ob[0];
        gload_lds16(Bg0 + kt * 32, &Bs[t * 8]);
        gload_lds16(Bg1 + kt * 32, &Bs[2048 + t * 8]);
        __syncthreads();
        if (kt < NT32 - 1) {
            int ko = (kt + 1) * 32;
            xa0 = *(const float4*)(Agf0 + ko);
            xa1 = *(const float4*)(Agf0 + ko + 4);
            xb0 = *(const float4*)(Agf1 + ko);
            xb1 = *(const float4*)(Agf1 + ko + 4);
        }
        bf16x8 a[4], b[4];
        int ro = (lane & 15) * 32 + (lane >> 4) * 8;
#pragma unroll
        for (int i = 0; i < 4; ++i)
            a[i] = *(const bf16x8*)&As[(wr * 64 + i * 16) * 32 + ro];
#pragma unroll
        for (int j = 0; j < 4; ++j)
            b[j] = *(const bf16x8*)&Bs[(wc * 64 + j * 16) * 32 + ro];
#pragma unroll
        for (int i = 0; i < 4; ++i)
#pragma unroll
            for (int j = 0; j < 4; ++j)
                acc[i][j] = __builtin_amdgcn_mfma_f32_16x16x32_bf16(a[i], b[j], acc[i][j], 0, 0, 0);
    }
    int col0 = n0 + wc * 64 + (lane & 15);
    int row0 = m0 + wr * 64 + (lane >> 4) * 4;
#pragma unroll
    for (int i = 0; i < 4; ++i)
#pragma unroll
        for (int j = 0; j < 4; ++j) {
            f32x4 v = acc[i][j];
            int r = row0 + i * 16, c = col0 + j * 16;
#pragma unroll
            for (int q = 0; q < 4; ++q)
                out[(size_t)(r + q) * N_TOTAL + c] = v[q];
        }
}

extern "C" void kernel_launch(void* const* d_in, const int* in_sizes, int n_in,
                              void* d_out, int out_size, void* d_ws, size_t ws_size,
                              hipStream_t stream) {
    const float* X = (const float*)d_in[0];
    const int* PW = (const int*)d_in[1];
    const float* SC = (const float*)d_in[2];
    float* OUT = (float*)d_out;

    const size_t needW = (size_t)N_TOTAL * K_TOTAL * 2;            // 33.5 MB
    const size_t needX = needW + (size_t)M_TOTAL * K_TOTAL * 2;    // +134 MB

    if (ws_size >= needX) {
        __hip_bfloat16* Wb = (__hip_bfloat16*)d_ws;
        __hip_bfloat16* Xb = (__hip_bfloat16*)((char*)d_ws + needW);
        k_convX<<<dim3(32768), dim3(256), 0, stream>>>(X, Xb);
        k_dequant<<<dim3(4096), dim3(256), 0, stream>>>(PW, SC, Wb);
        k_gemm22<<<dim3((M_TOTAL / 256) * (N_TOTAL / 256)), dim3(512), 0, stream>>>(Xb, Wb, OUT);
    } else if (ws_size >= needW) {
        __hip_bfloat16* Wb = (__hip_bfloat16*)d_ws;
        k_dequant<<<dim3(4096), dim3(256), 0, stream>>>(PW, SC, Wb);
        k_gemm2b<<<dim3((M_TOTAL / 128) * (N_TOTAL / 128)), dim3(256), 0, stream>>>(X, Wb, OUT);
    }
}